// Round 13
// baseline (177.391 us; speedup 1.0000x reference)
//
#include <hip/hip_runtime.h>
#include <hip/hip_bf16.h>

#define RR 257
#define RP 288
#define TT 21

typedef __attribute__((ext_vector_type(4))) float f32x4;
typedef __attribute__((ext_vector_type(8))) short bf16x8;

union Pack8 { unsigned short s[8]; uint4 v; };
union FragU { unsigned w[4]; bf16x8 v; };

__device__ __forceinline__ unsigned short f2b(float f) {
    union { float f; unsigned u; } v; v.f = f;
    unsigned r = v.u + 0x7fffu + ((v.u >> 16) & 1u);
    return (unsigned short)(r >> 16);
}

__device__ __forceinline__ unsigned cvtpk(float lo, float hi) {
    unsigned r;
    asm("v_cvt_pk_bf16_f32 %0, %1, %2" : "=v"(r) : "v"(lo), "v"(hi));
    return r;
}

// Stage 1: p{1,2,3}[n,row,r] = concat(layer,1) @ W (r zero-padded to 288).
// P1 written ROW-MAJOR f32; P2/P3 written FRAGMENT-ORDERED f32:
//   Pf[((n*6 + rg)*9 + ks)*512 + (hi*16 + (row&15))*8 + e],
//   rg=row>>4, ks=r>>5, hi=(r>>3)&3, e=r&7.
__global__ __launch_bounds__(384) void proj_kernel(
    const float* __restrict__ l1, const float* __restrict__ l2, const float* __restrict__ l3,
    const float* __restrict__ W1, const float* __restrict__ W2, const float* __restrict__ W3,
    float* __restrict__ P1f, float* __restrict__ P2f, float* __restrict__ P3f)
{
    int bx = blockIdx.x;           // 3 streams * 4 n * 48 row-groups (2 rows each)
    int grp = bx % 48;
    int n = (bx / 48) & 3;
    int s = bx / 192;
    const float* layer = (s == 0) ? l1 : (s == 1) ? l2 : l3;
    const float* W     = (s == 0) ? W1 : (s == 1) ? W2 : W3;
    int i0 = grp * 2;

    __shared__ __attribute__((aligned(16))) float x[1024];  // 2 rows x 512
    const float4* src = (const float4*)(layer + (n * 96 + i0) * 512);
    float4* xv = (float4*)x;
    for (int idx = threadIdx.x; idx < 256; idx += 384) xv[idx] = src[idx];
    __syncthreads();

    int r = threadIdx.x;
    if (r < RP) {
        float a0 = 0.f, a1 = 0.f;
        if (r < RR) {
            float b = W[512 * RR + r];     // bias-ones row
            a0 = a1 = b;
            #pragma unroll 8
            for (int a = 0; a < 512; ++a) {
                float wa = W[a * RR + r];
                a0 = fmaf(x[a], wa, a0);
                a1 = fmaf(x[512 + a], wa, a1);
            }
        }
        if (s == 0) {
            int base = (n * 96 + i0) * RP + r;
            P1f[base]      = a0;
            P1f[base + RP] = a1;
        } else {
            float* P = (s == 1) ? P2f : P3f;
            int ks = r >> 5, hi = (r >> 3) & 3, e = r & 7;
            #pragma unroll
            for (int q = 0; q < 2; ++q) {
                int row = i0 + q;
                int rg = row >> 4, Llo = row & 15;
                P[(size_t)((n * 6 + rg) * 9 + ks) * 512 + (hi * 16 + Llo) * 8 + e]
                    = q ? a1 : a0;
            }
        }
    }
}

// per-rg p2 raw loads for K-step kss into buffer s
#define LOADP(s, kss) { \
    _Pragma("unroll") for (int q = 0; q < 3; ++q) { \
        const float* pp = p2base + (size_t)(q * 9 + (kss)) * 512; \
        rp2[s][q][0] = *(const f32x4*)(pp); \
        rp2[s][q][1] = *(const f32x4*)(pp + 4); } \
    rp1[s][0] = *(const f32x4*)(p1base + (kss) * 32); \
    rp1[s][1] = *(const f32x4*)(p1base + (kss) * 32 + 4); }

// convert raw f32 (arrived during previous MFMAs) -> fa bf16 fragments
#define CONV(s) { \
    _Pragma("unroll") for (int q = 0; q < 3; ++q) { \
        f32x4 h0 = rp1[s][0] * rp2[s][q][0]; \
        f32x4 h1 = rp1[s][1] * rp2[s][q][1]; \
        FragU u; \
        u.w[0] = cvtpk(h0[0], h0[1]); u.w[1] = cvtpk(h0[2], h0[3]); \
        u.w[2] = cvtpk(h1[0], h1[1]); u.w[3] = cvtpk(h1[2], h1[3]); \
        fa[q] = u.v; } }

#define LOADFB(kss) { _Pragma("unroll") for (int nf = 0; nf < 6; ++nf) \
    fb[nf] = *(const bf16x8*)(lbase + (nf * 9 + (kss)) * 512); }

#define MFMAS() { _Pragma("unroll") for (int mf = 0; mf < 3; ++mf) { \
    _Pragma("unroll") for (int nf = 0; nf < 6; ++nf) \
      acc[mf][nf] = __builtin_amdgcn_mfma_f32_16x16x32_bf16(fb[nf], fa[mf], acc[mf][nf], 0, 0, 0); } }

// Stage 2 (fully fused): per block (n,t,mt): C[192,96] = A'[192,288]*B[96,288]^T.
// B formed once in LDS from P3frag x wl; A formed per-K-step in registers from
// P1-row broadcast x P2frag (48-row wave tiles are i-aligned: i = 2*mt + wv/2).
__global__ __launch_bounds__(256, 2) void tri13_kernel(
    const float* __restrict__ P1f, const float* __restrict__ P2f,
    const float* __restrict__ P3f, const float* __restrict__ Wl,
    float* __restrict__ out)
{
    int orig = blockIdx.x;
    if (orig < 2048) {   // one-time phase stagger for initially-resident set
        int key = ((orig >> 3) ^ (orig >> 8)) & 7;
        for (int d = 0; d < key; ++d) __builtin_amdgcn_s_sleep(16);
    }
    // 4032 = 8 XCDs * 504; bijective chunked swizzle; t fastest (A-side L2 reuse).
    int bx = (orig & 7) * 504 + (orig >> 3);
    int t = bx % TT;
    int mtn = bx / TT;             // 0..191
    int mt = mtn % 48;
    int n = mtn / 48;

    int tid = threadIdx.x, lane = tid & 63, wv = tid >> 6;

    __shared__ __attribute__((aligned(16))) unsigned short blds[27648];  // 54 KB
    __shared__ __attribute__((aligned(16))) float tbuf[4][1600];         // 25.6 KB
    __shared__ __attribute__((aligned(16))) float wl_lds[RP];

    for (int r = tid; r < RP; r += 256)
        wl_lds[r] = (r < RR) ? Wl[r * TT + t] : 0.f;
    __syncthreads();

    // Form B = p3 (.) wl -> bf16 fragment-ordered in LDS (one rounding).
    for (int idx = tid; idx < 3456; idx += 256) {
        int L = idx & 63;
        int rest = idx >> 6;
        int ks = rest % 9, kg = rest / 9;
        const float* pp = P3f + (size_t)((n * 6 + kg) * 9 + ks) * 512 + L * 8;
        float4 p0 = *(const float4*)(pp);
        float4 p1v = *(const float4*)(pp + 4);
        int r0 = ks * 32 + (L >> 4) * 8;
        float4 w0 = *(const float4*)(wl_lds + r0);
        float4 w1 = *(const float4*)(wl_lds + r0 + 4);
        Pack8 u;
        u.s[0] = f2b(p0.x * w0.x); u.s[1] = f2b(p0.y * w0.y);
        u.s[2] = f2b(p0.z * w0.z); u.s[3] = f2b(p0.w * w0.w);
        u.s[4] = f2b(p1v.x * w1.x); u.s[5] = f2b(p1v.y * w1.y);
        u.s[6] = f2b(p1v.z * w1.z); u.s[7] = f2b(p1v.w * w1.w);
        *(uint4*)(blds + (size_t)(kg * 9 + ks) * 512 + L * 8) = u.v;
    }
    __syncthreads();

    // Wave tile: 48 rows (3 rg), i constant: i = 2*mt + (wv>>1), j0 = (wv&1)*48.
    int i = 2 * mt + (wv >> 1);
    int rgj = (wv & 1) * 3;
    const float* p2base = P2f + (size_t)((n * 6 + rgj) * 9) * 512 + lane * 8;
    const float* p1base = P1f + (size_t)(n * 96 + i) * RP + (lane >> 4) * 8;
    const unsigned short* lbase = blds + lane * 8;

    f32x4 acc[3][6] = {};
    f32x4 rp2[2][3][2], rp1[2][2];
    bf16x8 fa[3], fb[6];

    LOADP(0, 0);
    #pragma unroll
    for (int ks = 0; ks < 9; ++ks) {
        int cur = ks & 1, nxt = cur ^ 1;
        if (ks < 8) {
            if (cur) { LOADP(0, ks + 1); } else { LOADP(1, ks + 1); }
        }
        if (cur) { CONV(1); } else { CONV(0); }
        LOADFB(ks);
        MFMAS();
    }

    // Epilogue: per-wave LDS transpose (pitch 100, conflict-free b128), then
    // contiguous f32x4 NT stores (1 KB/instruction = 8 full 128B lines).
    float* tb = tbuf[wv];
    int Llo = lane & 15, Lhi = lane >> 4;
    size_t outbase = ((size_t)(n * TT + t) * 9216 + mt * 192 + wv * 48) * 96;

    #pragma unroll
    for (int mf = 0; mf < 3; ++mf) {
        #pragma unroll
        for (int nf = 0; nf < 6; ++nf)
            *(f32x4*)&tb[Llo * 100 + nf * 16 + Lhi * 4] = acc[mf][nf];
        float* gdst = out + outbase + (size_t)mf * 16 * 96;
        #pragma unroll
        for (int q = 0; q < 6; ++q) {
            int fidx = q * 64 + lane;
            int ml = fidx / 24, k4 = fidx % 24;
            f32x4 vv = *(const f32x4*)&tb[ml * 100 + k4 * 4];
            __builtin_nontemporal_store(vv, (f32x4*)(gdst + (size_t)fidx * 4));
        }
    }
}

extern "C" void kernel_launch(void* const* d_in, const int* in_sizes, int n_in,
                              void* d_out, int out_size, void* d_ws, size_t ws_size,
                              hipStream_t stream) {
    const float* l1 = (const float*)d_in[0];
    const float* l2 = (const float*)d_in[1];
    const float* l3 = (const float*)d_in[2];
    const float* W1 = (const float*)d_in[3];
    const float* W2 = (const float*)d_in[4];
    const float* W3 = (const float*)d_in[5];
    const float* Wl = (const float*)d_in[6];

    float* P1f = (float*)d_ws;                 // 384*288 f32 row-major
    float* P2f = P1f + 384 * RP;               // 4*6*9*512 f32 fragment-ordered
    float* P3f = P2f + 4 * 6 * 9 * 512;        // same
    // total ws use ~1.3 MB

    proj_kernel<<<576, 384, 0, stream>>>(l1, l2, l3, W1, W2, W3, P1f, P2f, P3f);
    tri13_kernel<<<4032, 256, 0, stream>>>(P1f, P2f, P3f, Wl, (float*)d_out);
}

// Round 14
// 121.373 us; speedup vs baseline: 1.4615x; 1.4615x over previous
//
#include <hip/hip_runtime.h>
#include <hip/hip_bf16.h>

#define RR 257
#define RP 288
#define TT 21

typedef __attribute__((ext_vector_type(4))) float f32x4;
typedef __attribute__((ext_vector_type(8))) short bf16x8;

union Pack8 { unsigned short s[8]; uint4 v; };

__device__ __forceinline__ unsigned short f2b(float f) {
    union { float f; unsigned u; } v; v.f = f;
    unsigned r = v.u + 0x7fffu + ((v.u >> 16) & 1u);
    return (unsigned short)(r >> 16);
}

// Stage 1: p{1,2,3}[n,i,r] = concat(layer,1) @ W (r padded to 288), f32.
__global__ __launch_bounds__(384) void proj_kernel(
    const float* __restrict__ l1, const float* __restrict__ l2, const float* __restrict__ l3,
    const float* __restrict__ W1, const float* __restrict__ W2, const float* __restrict__ W3,
    float* __restrict__ P1f, float* __restrict__ P2f, float* __restrict__ P3f)
{
    int bx = blockIdx.x;           // 3 streams * 4 n * 48 row-groups (2 rows each)
    int grp = bx % 48;
    int n = (bx / 48) & 3;
    int s = bx / 192;
    const float* layer = (s == 0) ? l1 : (s == 1) ? l2 : l3;
    const float* W     = (s == 0) ? W1 : (s == 1) ? W2 : W3;
    int i0 = grp * 2;

    __shared__ __attribute__((aligned(16))) float x[1024];  // 2 rows x 512
    const float4* src = (const float4*)(layer + (n * 96 + i0) * 512);
    float4* xv = (float4*)x;
    for (int idx = threadIdx.x; idx < 256; idx += 384) xv[idx] = src[idx];
    __syncthreads();

    int r = threadIdx.x;
    if (r < RP) {
        float a0 = 0.f, a1 = 0.f;
        if (r < RR) {
            float b = W[512 * RR + r];     // bias-ones row
            a0 = a1 = b;
            #pragma unroll 8
            for (int a = 0; a < 512; ++a) {
                float wa = W[a * RR + r];
                a0 = fmaf(x[a], wa, a0);
                a1 = fmaf(x[512 + a], wa, a1);
            }
        }
        float* P = (s == 0) ? P1f : (s == 1) ? P2f : P3f;
        int base = (n * 96 + i0) * RP + r;
        P[base]      = a0;
        P[base + RP] = a1;
    }
}

// Stage 1.5 (fused): blocks 0..383 build A' (p1*p2); 384..551 build B (p3*wl).
// Both stored FRAGMENT-ORDERED bf16:
// Af[((n*576 + rg)*9 + ks)*512 + L*8 + e] = A'[rg*16 + (L&15)][ks*32 + (L>>4)*8 + e]
__global__ __launch_bounds__(256) void prep_kernel(
    const float* __restrict__ P1f, const float* __restrict__ P2f,
    const float* __restrict__ P3f, const float* __restrict__ Wl,
    unsigned short* __restrict__ Af, unsigned short* __restrict__ Bf)
{
    int bx = blockIdx.x;
    if (bx < 384) {
        int n = bx / 96, i = bx % 96;
        __shared__ __attribute__((aligned(16))) float p1row[RP];
        for (int r = threadIdx.x; r < RP; r += 256)
            p1row[r] = P1f[(n * 96 + i) * RP + r];
        __syncthreads();

        unsigned short* dst = Af + (size_t)(n * 576 + i * 6) * 9 * 512;
        for (int idx = threadIdx.x; idx < 3456; idx += 256) {
            int L = idx & 63;
            int rest = idx >> 6;            // 0..53
            int ks = rest % 9, rgl = rest / 9;
            int j = rgl * 16 + (L & 15);
            int k8 = ks * 32 + (L >> 4) * 8;
            const float* p2p = P2f + (n * 96 + j) * RP + k8;
            float4 b0 = *(const float4*)(p2p);
            float4 b1 = *(const float4*)(p2p + 4);
            float4 a0 = *(const float4*)(p1row + k8);
            float4 a1 = *(const float4*)(p1row + k8 + 4);
            Pack8 u;
            u.s[0] = f2b(a0.x * b0.x); u.s[1] = f2b(a0.y * b0.y);
            u.s[2] = f2b(a0.z * b0.z); u.s[3] = f2b(a0.w * b0.w);
            u.s[4] = f2b(a1.x * b1.x); u.s[5] = f2b(a1.y * b1.y);
            u.s[6] = f2b(a1.z * b1.z); u.s[7] = f2b(a1.w * b1.w);
            *(uint4*)(dst + (size_t)(rgl * 9 + ks) * 512 + L * 8) = u.v;
        }
    } else {
        int b2 = bx - 384;
        int h = b2 & 1;
        int t = (b2 >> 1) % TT, n = b2 / (2 * TT);
        __shared__ __attribute__((aligned(16))) float wl_lds[RP];
        for (int r = threadIdx.x; r < RP; r += 256)
            wl_lds[r] = (r < RR) ? Wl[r * TT + t] : 0.f;
        __syncthreads();

        unsigned short* dst = Bf + (size_t)(n * TT + t) * 6 * 9 * 512;
        for (int idx2 = threadIdx.x; idx2 < 1728; idx2 += 256) {
            int idx = h * 1728 + idx2;
            int L = idx & 63;
            int rest = idx >> 6;
            int ks = rest % 9, kg = rest / 9;
            int col = kg * 16 + (L & 15);
            int r8 = ks * 32 + (L >> 4) * 8;
            const float* p3p = P3f + (n * 96 + col) * RP + r8;
            float4 p0 = *(const float4*)(p3p);
            float4 p1 = *(const float4*)(p3p + 4);
            float4 w0 = *(const float4*)(wl_lds + r8);
            float4 w1 = *(const float4*)(wl_lds + r8 + 4);
            Pack8 u;
            u.s[0] = f2b(p0.x * w0.x); u.s[1] = f2b(p0.y * w0.y);
            u.s[2] = f2b(p0.z * w0.z); u.s[3] = f2b(p0.w * w0.w);
            u.s[4] = f2b(p1.x * w1.x); u.s[5] = f2b(p1.y * w1.y);
            u.s[6] = f2b(p1.z * w1.z); u.s[7] = f2b(p1.w * w1.w);
            *(uint4*)(dst + (size_t)(kg * 9 + ks) * 512 + L * 8) = u.v;
        }
    }
}

#define LOADA(s, kss) { _Pragma("unroll") for (int mf = 0; mf < 4; ++mf) \
    fa[s][mf] = *(const bf16x8*)(abase + (mf * 9 + (kss)) * 512); }
#define LOADB(s, kss) { _Pragma("unroll") for (int nf = 0; nf < 6; ++nf) \
    fb[s][nf] = *(const bf16x8*)(bbase + (nf * 9 + (kss)) * 512); }
#define MFMAS(s) { _Pragma("unroll") for (int mf = 0; mf < 4; ++mf) { \
    _Pragma("unroll") for (int nf = 0; nf < 6; ++nf) \
      acc[mf][nf] = __builtin_amdgcn_mfma_f32_16x16x32_bf16(fb[s][nf], fa[s][mf], acc[mf][nf], 0, 0, 0); } }

// Stage 2: byte-identical to round-12 tri12 EXCEPT block decode is M-FASTEST:
// for fixed (n,t), 144 consecutive blocks on one XCD write a CONTIGUOUS 3.5MB
// output plane sequentially (long HBM write streams, fill-kernel-like), and
// share one 54KB B slab (L2-resident reads). Single-variable locality test.
__global__ __launch_bounds__(64, 2) void tri14_kernel(
    const unsigned short* __restrict__ Af, const unsigned short* __restrict__ Bf,
    float* __restrict__ out)
{
    int orig = blockIdx.x;
    // One-time phase stagger for the initially-resident set (~first 2048 blocks).
    if (orig < 2048) {
        int key = ((orig >> 3) ^ (orig >> 8)) & 7;
        for (int d = 0; d < key; ++d) __builtin_amdgcn_s_sleep(16);
    }
    // 12096 = 8 XCDs * 1512; bijective chunked swizzle; mt FASTEST (write locality).
    int bx = (orig & 7) * 1512 + (orig >> 3);
    int mt = bx % 144;
    int rest = bx / 144;           // 0..83
    int t = rest % TT;
    int n = rest / TT;

    int lane = threadIdx.x & 63;

    const unsigned short* abase =
        Af + (size_t)(n * 576 + mt * 4) * 9 * 512 + lane * 8;
    const unsigned short* bbase =
        Bf + (size_t)(n * TT + t) * 27648 + lane * 8;

    f32x4 acc[4][6] = {};
    bf16x8 fa[2][4], fb[2][6];

    LOADA(0, 0); LOADB(0, 0);
    #pragma unroll
    for (int kp = 0; kp < 4; ++kp) {
        LOADA(1, 2 * kp + 1); LOADB(1, 2 * kp + 1);
        MFMAS(0);
        LOADA(0, 2 * kp + 2); LOADB(0, 2 * kp + 2);
        MFMAS(1);
    }
    MFMAS(0);   // ks = 8

    // Epilogue: per-wave LDS transpose (pitch 100, conflict-free b128), then
    // contiguous f32x4 NT stores (1 KB/instruction = 8 full 128B lines).
    __shared__ __attribute__((aligned(16))) float tb[1600];
    int Llo = lane & 15, Lhi = lane >> 4;
    size_t outbase = ((size_t)(n * TT + t) * 9216 + mt * 64) * 96;

    #pragma unroll
    for (int mf = 0; mf < 4; ++mf) {
        #pragma unroll
        for (int nf = 0; nf < 6; ++nf)
            *(f32x4*)&tb[Llo * 100 + nf * 16 + Lhi * 4] = acc[mf][nf];
        float* gdst = out + outbase + (size_t)mf * 16 * 96;
        #pragma unroll
        for (int q = 0; q < 6; ++q) {
            int fidx = q * 64 + lane;
            int ml = fidx / 24, k4 = fidx % 24;
            f32x4 vv = *(const f32x4*)&tb[ml * 100 + k4 * 4];
            __builtin_nontemporal_store(vv, (f32x4*)(gdst + (size_t)fidx * 4));
        }
    }
}

extern "C" void kernel_launch(void* const* d_in, const int* in_sizes, int n_in,
                              void* d_out, int out_size, void* d_ws, size_t ws_size,
                              hipStream_t stream) {
    const float* l1 = (const float*)d_in[0];
    const float* l2 = (const float*)d_in[1];
    const float* l3 = (const float*)d_in[2];
    const float* W1 = (const float*)d_in[3];
    const float* W2 = (const float*)d_in[4];
    const float* W3 = (const float*)d_in[5];
    const float* Wl = (const float*)d_in[6];

    float* P1f = (float*)d_ws;                 // 3 x 384*288 f32
    float* P2f = P1f + 384 * RP;
    float* P3f = P2f + 384 * RP;
    unsigned short* Af = (unsigned short*)(P3f + 384 * RP);  // 4*576*9*512 bf16 = 21.2 MB
    unsigned short* Bf = Af + (size_t)4 * 576 * 9 * 512;     // 4*21*6*9*512 bf16 = 4.65 MB

    proj_kernel<<<576, 384, 0, stream>>>(l1, l2, l3, W1, W2, W3, P1f, P2f, P3f);
    prep_kernel<<<552, 256, 0, stream>>>(P1f, P2f, P3f, Wl, Af, Bf);
    tri14_kernel<<<12096, 64, 0, stream>>>(Af, Bf, (float*)d_out);
}

// Round 15
// 118.736 us; speedup vs baseline: 1.4940x; 1.0222x over previous
//
#include <hip/hip_runtime.h>
#include <hip/hip_bf16.h>

#define RR 257
#define RP 288
#define TT 21

typedef __attribute__((ext_vector_type(4))) float f32x4;
typedef __attribute__((ext_vector_type(8))) short bf16x8;

union Pack8 { unsigned short s[8]; uint4 v; };

__device__ __forceinline__ unsigned short f2b(float f) {
    union { float f; unsigned u; } v; v.f = f;
    unsigned r = v.u + 0x7fffu + ((v.u >> 16) & 1u);
    return (unsigned short)(r >> 16);
}

// Stage 1: p{1,2,3}[n,i,r] = concat(layer,1) @ W (r padded to 288), f32.
__global__ __launch_bounds__(384) void proj_kernel(
    const float* __restrict__ l1, const float* __restrict__ l2, const float* __restrict__ l3,
    const float* __restrict__ W1, const float* __restrict__ W2, const float* __restrict__ W3,
    float* __restrict__ P1f, float* __restrict__ P2f, float* __restrict__ P3f)
{
    int bx = blockIdx.x;           // 3 streams * 4 n * 48 row-groups (2 rows each)
    int grp = bx % 48;
    int n = (bx / 48) & 3;
    int s = bx / 192;
    const float* layer = (s == 0) ? l1 : (s == 1) ? l2 : l3;
    const float* W     = (s == 0) ? W1 : (s == 1) ? W2 : W3;
    int i0 = grp * 2;

    __shared__ __attribute__((aligned(16))) float x[1024];  // 2 rows x 512
    const float4* src = (const float4*)(layer + (n * 96 + i0) * 512);
    float4* xv = (float4*)x;
    for (int idx = threadIdx.x; idx < 256; idx += 384) xv[idx] = src[idx];
    __syncthreads();

    int r = threadIdx.x;
    if (r < RP) {
        float a0 = 0.f, a1 = 0.f;
        if (r < RR) {
            float b = W[512 * RR + r];     // bias-ones row
            a0 = a1 = b;
            #pragma unroll 8
            for (int a = 0; a < 512; ++a) {
                float wa = W[a * RR + r];
                a0 = fmaf(x[a], wa, a0);
                a1 = fmaf(x[512 + a], wa, a1);
            }
        }
        float* P = (s == 0) ? P1f : (s == 1) ? P2f : P3f;
        int base = (n * 96 + i0) * RP + r;
        P[base]      = a0;
        P[base + RP] = a1;
    }
}

// Stage 1.5 (fused): blocks 0..383 build A' (p1*p2); 384..551 build B (p3*wl).
// Both stored FRAGMENT-ORDERED bf16:
// Af[((n*576 + rg)*9 + ks)*512 + L*8 + e] = A'[rg*16 + (L&15)][ks*32 + (L>>4)*8 + e]
__global__ __launch_bounds__(256) void prep_kernel(
    const float* __restrict__ P1f, const float* __restrict__ P2f,
    const float* __restrict__ P3f, const float* __restrict__ Wl,
    unsigned short* __restrict__ Af, unsigned short* __restrict__ Bf)
{
    int bx = blockIdx.x;
    if (bx < 384) {
        int n = bx / 96, i = bx % 96;
        __shared__ __attribute__((aligned(16))) float p1row[RP];
        for (int r = threadIdx.x; r < RP; r += 256)
            p1row[r] = P1f[(n * 96 + i) * RP + r];
        __syncthreads();

        unsigned short* dst = Af + (size_t)(n * 576 + i * 6) * 9 * 512;
        for (int idx = threadIdx.x; idx < 3456; idx += 256) {
            int L = idx & 63;
            int rest = idx >> 6;            // 0..53
            int ks = rest % 9, rgl = rest / 9;
            int j = rgl * 16 + (L & 15);
            int k8 = ks * 32 + (L >> 4) * 8;
            const float* p2p = P2f + (n * 96 + j) * RP + k8;
            float4 b0 = *(const float4*)(p2p);
            float4 b1 = *(const float4*)(p2p + 4);
            float4 a0 = *(const float4*)(p1row + k8);
            float4 a1 = *(const float4*)(p1row + k8 + 4);
            Pack8 u;
            u.s[0] = f2b(a0.x * b0.x); u.s[1] = f2b(a0.y * b0.y);
            u.s[2] = f2b(a0.z * b0.z); u.s[3] = f2b(a0.w * b0.w);
            u.s[4] = f2b(a1.x * b1.x); u.s[5] = f2b(a1.y * b1.y);
            u.s[6] = f2b(a1.z * b1.z); u.s[7] = f2b(a1.w * b1.w);
            *(uint4*)(dst + (size_t)(rgl * 9 + ks) * 512 + L * 8) = u.v;
        }
    } else {
        int b2 = bx - 384;
        int h = b2 & 1;
        int t = (b2 >> 1) % TT, n = b2 / (2 * TT);
        __shared__ __attribute__((aligned(16))) float wl_lds[RP];
        for (int r = threadIdx.x; r < RP; r += 256)
            wl_lds[r] = (r < RR) ? Wl[r * TT + t] : 0.f;
        __syncthreads();

        unsigned short* dst = Bf + (size_t)(n * TT + t) * 6 * 9 * 512;
        for (int idx2 = threadIdx.x; idx2 < 1728; idx2 += 256) {
            int idx = h * 1728 + idx2;
            int L = idx & 63;
            int rest = idx >> 6;
            int ks = rest % 9, kg = rest / 9;
            int col = kg * 16 + (L & 15);
            int r8 = ks * 32 + (L >> 4) * 8;
            const float* p3p = P3f + (n * 96 + col) * RP + r8;
            float4 p0 = *(const float4*)(p3p);
            float4 p1 = *(const float4*)(p3p + 4);
            float4 w0 = *(const float4*)(wl_lds + r8);
            float4 w1 = *(const float4*)(wl_lds + r8 + 4);
            Pack8 u;
            u.s[0] = f2b(p0.x * w0.x); u.s[1] = f2b(p0.y * w0.y);
            u.s[2] = f2b(p0.z * w0.z); u.s[3] = f2b(p0.w * w0.w);
            u.s[4] = f2b(p1.x * w1.x); u.s[5] = f2b(p1.y * w1.y);
            u.s[6] = f2b(p1.z * w1.z); u.s[7] = f2b(p1.w * w1.w);
            *(uint4*)(dst + (size_t)(kg * 9 + ks) * 512 + L * 8) = u.v;
        }
    }
}

#define LOADA(s, kss) { _Pragma("unroll") for (int mf = 0; mf < 3; ++mf) \
    fa[s][mf] = *(const bf16x8*)(abase + (mf * 9 + (kss)) * 512); }
#define LOADB(s, kss) { _Pragma("unroll") for (int nf = 0; nf < 6; ++nf) \
    fb[s][nf] = *(const bf16x8*)(bbase + (nf * 9 + (kss)) * 512); }
#define MFMAS(s) { _Pragma("unroll") for (int mf = 0; mf < 3; ++mf) { \
    _Pragma("unroll") for (int nf = 0; nf < 6; ++nf) \
      acc[mf][nf] = __builtin_amdgcn_mfma_f32_16x16x32_bf16(fb[s][nf], fa[s][mf], acc[mf][nf], 0, 0, 0); } }

// Stage 2: r12's structure with a 48x96 wave tile (~165 VGPR) -> 3 waves/SIMD,
// 12 single-wave blocks/CU: +50% concurrent store streams. Single-variable test
// of the store-concurrency cap. Everything else identical to tri12.
__global__ __launch_bounds__(64, 3) void tri15_kernel(
    const unsigned short* __restrict__ Af, const unsigned short* __restrict__ Bf,
    float* __restrict__ out)
{
    int orig = blockIdx.x;
    // One-time phase stagger for the initially-resident set (~first 3072 blocks).
    if (orig < 3072) {
        int key = ((orig >> 3) ^ (orig >> 8)) & 7;
        for (int d = 0; d < key; ++d) __builtin_amdgcn_s_sleep(16);
    }
    // 16128 = 8 XCDs * 2016; bijective chunked swizzle; t fastest (A-slab L2 reuse).
    int bx = (orig & 7) * 2016 + (orig >> 3);
    int t = bx % TT;
    int mtn = bx / TT;             // 0..767
    int mt = mtn % 192;            // 192 M-tiles of 48 rows
    int n = mtn / 192;

    int lane = threadIdx.x & 63;

    const unsigned short* abase =
        Af + (size_t)(n * 576 + mt * 3) * 9 * 512 + lane * 8;
    const unsigned short* bbase =
        Bf + (size_t)(n * TT + t) * 27648 + lane * 8;

    f32x4 acc[3][6] = {};
    bf16x8 fa[2][3], fb[2][6];

    LOADA(0, 0); LOADB(0, 0);
    #pragma unroll
    for (int kp = 0; kp < 4; ++kp) {
        LOADA(1, 2 * kp + 1); LOADB(1, 2 * kp + 1);
        MFMAS(0);
        LOADA(0, 2 * kp + 2); LOADB(0, 2 * kp + 2);
        MFMAS(1);
    }
    MFMAS(0);   // ks = 8

    // Epilogue: per-wave LDS transpose (pitch 100, conflict-free b128), then
    // contiguous f32x4 NT stores (1 KB/instruction = 8 full 128B lines).
    __shared__ __attribute__((aligned(16))) float tb[1600];
    int Llo = lane & 15, Lhi = lane >> 4;
    size_t outbase = ((size_t)(n * TT + t) * 9216 + mt * 48) * 96;

    #pragma unroll
    for (int mf = 0; mf < 3; ++mf) {
        #pragma unroll
        for (int nf = 0; nf < 6; ++nf)
            *(f32x4*)&tb[Llo * 100 + nf * 16 + Lhi * 4] = acc[mf][nf];
        float* gdst = out + outbase + (size_t)mf * 16 * 96;
        #pragma unroll
        for (int q = 0; q < 6; ++q) {
            int fidx = q * 64 + lane;
            int ml = fidx / 24, k4 = fidx % 24;
            f32x4 vv = *(const f32x4*)&tb[ml * 100 + k4 * 4];
            __builtin_nontemporal_store(vv, (f32x4*)(gdst + (size_t)fidx * 4));
        }
    }
}

extern "C" void kernel_launch(void* const* d_in, const int* in_sizes, int n_in,
                              void* d_out, int out_size, void* d_ws, size_t ws_size,
                              hipStream_t stream) {
    const float* l1 = (const float*)d_in[0];
    const float* l2 = (const float*)d_in[1];
    const float* l3 = (const float*)d_in[2];
    const float* W1 = (const float*)d_in[3];
    const float* W2 = (const float*)d_in[4];
    const float* W3 = (const float*)d_in[5];
    const float* Wl = (const float*)d_in[6];

    float* P1f = (float*)d_ws;                 // 3 x 384*288 f32
    float* P2f = P1f + 384 * RP;
    float* P3f = P2f + 384 * RP;
    unsigned short* Af = (unsigned short*)(P3f + 384 * RP);  // 4*576*9*512 bf16 = 21.2 MB
    unsigned short* Bf = Af + (size_t)4 * 576 * 9 * 512;     // 4*21*6*9*512 bf16 = 4.65 MB

    proj_kernel<<<576, 384, 0, stream>>>(l1, l2, l3, W1, W2, W3, P1f, P2f, P3f);
    prep_kernel<<<552, 256, 0, stream>>>(P1f, P2f, P3f, Wl, Af, Bf);
    tri15_kernel<<<16128, 64, 0, stream>>>(Af, Bf, (float*)d_out);
}

// Round 16
// 111.579 us; speedup vs baseline: 1.5898x; 1.0641x over previous
//
#include <hip/hip_runtime.h>
#include <hip/hip_bf16.h>

#define RR 257
#define RP 288
#define TT 21

typedef __attribute__((ext_vector_type(4))) float f32x4;
typedef __attribute__((ext_vector_type(8))) short bf16x8;

union Pack8 { unsigned short s[8]; uint4 v; };

__device__ __forceinline__ unsigned short f2b(float f) {
    union { float f; unsigned u; } v; v.f = f;
    unsigned r = v.u + 0x7fffu + ((v.u >> 16) & 1u);
    return (unsigned short)(r >> 16);
}

// Stage 1: p{1,2,3}[n,i,r] = concat(layer,1) @ W (r padded to 288), f32.
__global__ __launch_bounds__(384) void proj_kernel(
    const float* __restrict__ l1, const float* __restrict__ l2, const float* __restrict__ l3,
    const float* __restrict__ W1, const float* __restrict__ W2, const float* __restrict__ W3,
    float* __restrict__ P1f, float* __restrict__ P2f, float* __restrict__ P3f)
{
    int bx = blockIdx.x;           // 3 streams * 4 n * 48 row-groups (2 rows each)
    int grp = bx % 48;
    int n = (bx / 48) & 3;
    int s = bx / 192;
    const float* layer = (s == 0) ? l1 : (s == 1) ? l2 : l3;
    const float* W     = (s == 0) ? W1 : (s == 1) ? W2 : W3;
    int i0 = grp * 2;

    __shared__ __attribute__((aligned(16))) float x[1024];  // 2 rows x 512
    const float4* src = (const float4*)(layer + (n * 96 + i0) * 512);
    float4* xv = (float4*)x;
    for (int idx = threadIdx.x; idx < 256; idx += 384) xv[idx] = src[idx];
    __syncthreads();

    int r = threadIdx.x;
    if (r < RP) {
        float a0 = 0.f, a1 = 0.f;
        if (r < RR) {
            float b = W[512 * RR + r];     // bias-ones row
            a0 = a1 = b;
            #pragma unroll 8
            for (int a = 0; a < 512; ++a) {
                float wa = W[a * RR + r];
                a0 = fmaf(x[a], wa, a0);
                a1 = fmaf(x[512 + a], wa, a1);
            }
        }
        float* P = (s == 0) ? P1f : (s == 1) ? P2f : P3f;
        int base = (n * 96 + i0) * RP + r;
        P[base]      = a0;
        P[base + RP] = a1;
    }
}

// Stage 1.5 (fused): blocks 0..383 build A' (p1*p2); 384..551 build B (p3*wl).
// Both stored FRAGMENT-ORDERED bf16:
// Af[((n*576 + rg)*9 + ks)*512 + L*8 + e] = A'[rg*16 + (L&15)][ks*32 + (L>>4)*8 + e]
__global__ __launch_bounds__(256) void prep_kernel(
    const float* __restrict__ P1f, const float* __restrict__ P2f,
    const float* __restrict__ P3f, const float* __restrict__ Wl,
    unsigned short* __restrict__ Af, unsigned short* __restrict__ Bf)
{
    int bx = blockIdx.x;
    if (bx < 384) {
        int n = bx / 96, i = bx % 96;
        __shared__ __attribute__((aligned(16))) float p1row[RP];
        for (int r = threadIdx.x; r < RP; r += 256)
            p1row[r] = P1f[(n * 96 + i) * RP + r];
        __syncthreads();

        unsigned short* dst = Af + (size_t)(n * 576 + i * 6) * 9 * 512;
        for (int idx = threadIdx.x; idx < 3456; idx += 256) {
            int L = idx & 63;
            int rest = idx >> 6;            // 0..53
            int ks = rest % 9, rgl = rest / 9;
            int j = rgl * 16 + (L & 15);
            int k8 = ks * 32 + (L >> 4) * 8;
            const float* p2p = P2f + (n * 96 + j) * RP + k8;
            float4 b0 = *(const float4*)(p2p);
            float4 b1 = *(const float4*)(p2p + 4);
            float4 a0 = *(const float4*)(p1row + k8);
            float4 a1 = *(const float4*)(p1row + k8 + 4);
            Pack8 u;
            u.s[0] = f2b(a0.x * b0.x); u.s[1] = f2b(a0.y * b0.y);
            u.s[2] = f2b(a0.z * b0.z); u.s[3] = f2b(a0.w * b0.w);
            u.s[4] = f2b(a1.x * b1.x); u.s[5] = f2b(a1.y * b1.y);
            u.s[6] = f2b(a1.z * b1.z); u.s[7] = f2b(a1.w * b1.w);
            *(uint4*)(dst + (size_t)(rgl * 9 + ks) * 512 + L * 8) = u.v;
        }
    } else {
        int b2 = bx - 384;
        int h = b2 & 1;
        int t = (b2 >> 1) % TT, n = b2 / (2 * TT);
        __shared__ __attribute__((aligned(16))) float wl_lds[RP];
        for (int r = threadIdx.x; r < RP; r += 256)
            wl_lds[r] = (r < RR) ? Wl[r * TT + t] : 0.f;
        __syncthreads();

        unsigned short* dst = Bf + (size_t)(n * TT + t) * 6 * 9 * 512;
        for (int idx2 = threadIdx.x; idx2 < 1728; idx2 += 256) {
            int idx = h * 1728 + idx2;
            int L = idx & 63;
            int rest = idx >> 6;
            int ks = rest % 9, kg = rest / 9;
            int col = kg * 16 + (L & 15);
            int r8 = ks * 32 + (L >> 4) * 8;
            const float* p3p = P3f + (n * 96 + col) * RP + r8;
            float4 p0 = *(const float4*)(p3p);
            float4 p1 = *(const float4*)(p3p + 4);
            float4 w0 = *(const float4*)(wl_lds + r8);
            float4 w1 = *(const float4*)(wl_lds + r8 + 4);
            Pack8 u;
            u.s[0] = f2b(p0.x * w0.x); u.s[1] = f2b(p0.y * w0.y);
            u.s[2] = f2b(p0.z * w0.z); u.s[3] = f2b(p0.w * w0.w);
            u.s[4] = f2b(p1.x * w1.x); u.s[5] = f2b(p1.y * w1.y);
            u.s[6] = f2b(p1.z * w1.z); u.s[7] = f2b(p1.w * w1.w);
            *(uint4*)(dst + (size_t)(kg * 9 + ks) * 512 + L * 8) = u.v;
        }
    }
}

#define LOADA(s, kss) { _Pragma("unroll") for (int mf = 0; mf < 4; ++mf) \
    fa[s][mf] = *(const bf16x8*)(abase + (mf * 9 + (kss)) * 512); }
#define LOADB(s, kss) { _Pragma("unroll") for (int nf = 0; nf < 6; ++nf) \
    fb[s][nf] = *(const bf16x8*)(bbase + (nf * 9 + (kss)) * 512); }
#define MFMAS(s) { _Pragma("unroll") for (int mf = 0; mf < 4; ++mf) { \
    _Pragma("unroll") for (int nf = 0; nf < 6; ++nf) \
      acc[mf][nf] = __builtin_amdgcn_mfma_f32_16x16x32_bf16(fb[s][nf], fa[s][mf], acc[mf][nf], 0, 0, 0); } }

// Stage 2: byte-identical to round-12 tri12 EXCEPT prefetch depth 2 -> 3:
// loads for K-step ks+2 are issued while MFMAs for ks run, so each step's
// MFMA cover (~240+ cy over 2 steps) exceeds L2-hit latency (~200-400 cy).
// fa[3][4]+fb[3][6] rotating buffers, fully unrolled (static indices).
// VGPR ~240 < 256 -> occupancy unchanged vs r12 (2 waves/SIMD, 8 blocks/CU).
__global__ __launch_bounds__(64, 2) void tri16_kernel(
    const unsigned short* __restrict__ Af, const unsigned short* __restrict__ Bf,
    float* __restrict__ out)
{
    int orig = blockIdx.x;
    // One-time phase stagger for the initially-resident set (~first 2048 blocks).
    if (orig < 2048) {
        int key = ((orig >> 3) ^ (orig >> 8)) & 7;
        for (int d = 0; d < key; ++d) __builtin_amdgcn_s_sleep(16);
    }
    // 12096 = 8 XCDs * 1512; bijective chunked swizzle; t fastest (A-slab L2 reuse).
    int bx = (orig & 7) * 1512 + (orig >> 3);
    int t = bx % TT;
    int mtn = bx / TT;             // 0..575
    int mt = mtn % 144;
    int n = mtn / 144;

    int lane = threadIdx.x & 63;

    const unsigned short* abase =
        Af + (size_t)(n * 576 + mt * 4) * 9 * 512 + lane * 8;
    const unsigned short* bbase =
        Bf + (size_t)(n * TT + t) * 27648 + lane * 8;

    f32x4 acc[4][6] = {};
    bf16x8 fa[3][4], fb[3][6];

    // 3-deep pipeline: prologue fills slots 0,1; steady state loads ks+2.
    LOADA(0, 0); LOADB(0, 0);
    LOADA(1, 1); LOADB(1, 1);

    LOADA(2, 2); LOADB(2, 2); MFMAS(0);   // ks=0
    LOADA(0, 3); LOADB(0, 3); MFMAS(1);   // ks=1
    LOADA(1, 4); LOADB(1, 4); MFMAS(2);   // ks=2
    LOADA(2, 5); LOADB(2, 5); MFMAS(0);   // ks=3
    LOADA(0, 6); LOADB(0, 6); MFMAS(1);   // ks=4
    LOADA(1, 7); LOADB(1, 7); MFMAS(2);   // ks=5
    LOADA(2, 8); LOADB(2, 8); MFMAS(0);   // ks=6
    MFMAS(1);                              // ks=7
    MFMAS(2);                              // ks=8

    // Epilogue: per-wave LDS transpose (pitch 100, conflict-free b128), then
    // contiguous f32x4 NT stores (1 KB/instruction = 8 full 128B lines).
    __shared__ __attribute__((aligned(16))) float tb[1600];
    int Llo = lane & 15, Lhi = lane >> 4;
    size_t outbase = ((size_t)(n * TT + t) * 9216 + mt * 64) * 96;

    #pragma unroll
    for (int mf = 0; mf < 4; ++mf) {
        #pragma unroll
        for (int nf = 0; nf < 6; ++nf)
            *(f32x4*)&tb[Llo * 100 + nf * 16 + Lhi * 4] = acc[mf][nf];
        float* gdst = out + outbase + (size_t)mf * 16 * 96;
        #pragma unroll
        for (int q = 0; q < 6; ++q) {
            int fidx = q * 64 + lane;
            int ml = fidx / 24, k4 = fidx % 24;
            f32x4 vv = *(const f32x4*)&tb[ml * 100 + k4 * 4];
            __builtin_nontemporal_store(vv, (f32x4*)(gdst + (size_t)fidx * 4));
        }
    }
}

extern "C" void kernel_launch(void* const* d_in, const int* in_sizes, int n_in,
                              void* d_out, int out_size, void* d_ws, size_t ws_size,
                              hipStream_t stream) {
    const float* l1 = (const float*)d_in[0];
    const float* l2 = (const float*)d_in[1];
    const float* l3 = (const float*)d_in[2];
    const float* W1 = (const float*)d_in[3];
    const float* W2 = (const float*)d_in[4];
    const float* W3 = (const float*)d_in[5];
    const float* Wl = (const float*)d_in[6];

    float* P1f = (float*)d_ws;                 // 3 x 384*288 f32
    float* P2f = P1f + 384 * RP;
    float* P3f = P2f + 384 * RP;
    unsigned short* Af = (unsigned short*)(P3f + 384 * RP);  // 4*576*9*512 bf16 = 21.2 MB
    unsigned short* Bf = Af + (size_t)4 * 576 * 9 * 512;     // 4*21*6*9*512 bf16 = 4.65 MB

    proj_kernel<<<576, 384, 0, stream>>>(l1, l2, l3, W1, W2, W3, P1f, P2f, P3f);
    prep_kernel<<<552, 256, 0, stream>>>(P1f, P2f, P3f, Wl, Af, Bf);
    tri16_kernel<<<12096, 64, 0, stream>>>(Af, Bf, (float*)d_out);
}